// Round 10
// baseline (570.336 us; speedup 1.0000x reference)
//
#include <hip/hip_runtime.h>
#include <hip/hip_bf16.h>
#include <cstdint>
#include <cstddef>

#define IN_CH 312
#define HID 256

typedef __attribute__((ext_vector_type(8))) short bf16x8;
typedef __attribute__((ext_vector_type(4))) float f32x4;
typedef __attribute__((ext_vector_type(8))) unsigned short ushort8;

__device__ __forceinline__ unsigned short f2bf(float f) {
    union { float f; unsigned u; } v; v.f = f;
    const unsigned r = v.u + 0x7FFFu + ((v.u >> 16) & 1u);  // RNE
    return (unsigned short)(r >> 16);
}
__device__ __forceinline__ float bf2f(unsigned short s) {
    union { unsigned u; float f; } v; v.u = (unsigned)s << 16;
    return v.f;
}

// ---------------------------------------------------------------------------
// Index dtype detector (int64 vs int32 edge_index).
// ---------------------------------------------------------------------------
__global__ void detect_idx_kernel(const void* __restrict__ ei, int* __restrict__ flag) {
    if (blockIdx.x == 0 && threadIdx.x == 0) {
        const int* p = (const int*)ei;
        int ok = 1;
        for (int i = 0; i < 64; ++i) ok &= (p[2 * i + 1] == 0);
        *flag = ok;
    }
}
__device__ __forceinline__ long long load_idx(const void* ei, long long i, bool is64) {
    return is64 ? ((const long long*)ei)[i] : (long long)((const int*)ei)[i];
}

// ---------------------------------------------------------------------------
// CSR build (unordered groups): histogram -> atomic group-offset assignment
// -> atomic-cursor fill. Group placement nondeterministic, membership exact.
// ---------------------------------------------------------------------------
__global__ void hist_kernel(const void* __restrict__ ei, const int* __restrict__ flag,
                            int* __restrict__ cnt, int E) {
    const int i = blockIdx.x * blockDim.x + threadIdx.x;
    if (i >= E) return;
    const bool is64 = (*flag != 0);
    atomicAdd(&cnt[load_idx(ei, (long long)E + i, is64)], 1);
}

__global__ void offsets_kernel(const int* __restrict__ cnt, int* __restrict__ counter,
                               int* __restrict__ beg, int* __restrict__ cur, int n) {
    const int i = blockIdx.x * blockDim.x + threadIdx.x;
    if (i >= n) return;
    const int b = atomicAdd(counter, cnt[i]);
    beg[i] = b;
    cur[i] = b;
}

__global__ void fill_kernel(const void* __restrict__ ei, const int* __restrict__ flag,
                            int* __restrict__ cur, int* __restrict__ col, int E) {
    const int i = blockIdx.x * blockDim.x + threadIdx.x;
    if (i >= E) return;
    const bool is64 = (*flag != 0);
    const long long s = load_idx(ei, i, is64);
    const long long d = load_idx(ei, (long long)E + i, is64);
    col[atomicAdd(&cur[d], 1)] = (int)s;
}

// ---------------------------------------------------------------------------
// Pack [Wl|Wr] into MFMA B-fragment order:
//   frag fi = k32*32 + c16 (c16 = col/16, k32 = k/32), slot = lane, 8 bf16.
//   wtp[fi*512 + l*8 + j] = W[k = k32*32 + (l>>4)*8 + j][col = c16*16 + (l&15)]
// A wave's bg load becomes ONE fully-coalesced 1KB read: base + lane*16B.
// ---------------------------------------------------------------------------
__global__ void pack_w_kernel(const float* __restrict__ Wl, const float* __restrict__ Wr,
                              unsigned short* __restrict__ wtp, int K, int Kpad) {
    const int tid = blockIdx.x * blockDim.x + threadIdx.x;
    const int total = (Kpad / 32) * 32 * 64;
    if (tid >= total) return;
    const int k32 = tid >> 11;           // /(32*64)
    const int rem = tid & 2047;
    const int c16 = rem >> 6;
    const int l   = rem & 63;
    const int col = c16 * 16 + (l & 15);
    const int kbase = k32 * 32 + (l >> 4) * 8;
    ushort8 o;
    #pragma unroll
    for (int j = 0; j < 8; ++j) {
        const int k = kbase + j;
        float v = 0.f;
        if (k < K) v = (col < 256) ? Wl[(size_t)k * 256 + col]
                                   : Wr[(size_t)k * 256 + (col - 256)];
        o[j] = f2bf(v);
    }
    *(ushort8*)(wtp + (size_t)tid * 8) = o;
}

// ---------------------------------------------------------------------------
// Register GEMM: NO LDS staging, NO barriers in the K-loop. Both operands load
// straight to registers; waves free-run and TLP hides L2/HBM latency (the R9
// barrier-drain pathology: 135us at 1.8TB/s, MfmaUtil 9.6, nothing busy).
// Tile 128x256 per block (8 waves, 4row x 2col, wave-tile 32x128), grid
// (M/128, 2): y=0 -> Y cols 0-255, y=1 -> Z cols 256-511.
//   B: packed fragments (pack_w_kernel), 1KB coalesced per load, L2-resident.
//   A: direct fragment gather; rows shared by wc=0/1 waves dedupe in L1.
//   AFP32: A fp32 [M][312] (x), convert in-reg. Else bf16 [M][KPAD=256] (h).
// Epilogue (proven R9): bf16 via LDS transpose -> ushort8 stores; layer-2 Z
// fp32 scalar in-place. LDS 33KB used ONLY in epilogue.
// ---------------------------------------------------------------------------
template <int KPAD, bool AFP32, bool ZBF16>
__global__ __launch_bounds__(512, 4) void reg_gemm_kernel(
    const void* __restrict__ Avoid,          // [M][312] f32 or [M][KPAD] bf16
    const unsigned short* __restrict__ WTP,  // packed frags
    const float* __restrict__ bias,          // [256]
    unsigned short* __restrict__ Y,          // [M][256] bf16
    void* __restrict__ Z,                    // [M][256] bf16 or fp32
    int M)
{
    __shared__ short c_lds[64 * 264];  // epilogue transpose only (33 KB)

    const int tid  = (int)threadIdx.x;
    const int lane = tid & 63;
    const int wid  = tid >> 6;              // 0..7
    const int wr = wid >> 1, wc = wid & 1;  // 4 wave-rows x 2 wave-cols
    const int r0 = blockIdx.x * 128;
    const int c0 = blockIdx.y * 256;        // 0 -> Y, 256 -> Z

    const int lrow = lane & 15;
    const int kgrp = lane >> 4;             // 0..3

    // clamped global rows for the two A fragments of this wave
    const int gr0 = min(r0 + wr * 32 + lrow, M - 1);
    const int gr1 = min(r0 + wr * 32 + 16 + lrow, M - 1);

    f32x4 acc[2][8];
    #pragma unroll
    for (int i = 0; i < 2; ++i)
        #pragma unroll
        for (int j = 0; j < 8; ++j) acc[i][j] = (f32x4)0.f;

    const int c16b = (c0 >> 4) + wc * 8;  // global 16-col fragment base

    for (int kb = 0; kb < KPAD; kb += 32) {
        const int k32 = kb >> 5;
        const int k0 = kb + kgrp * 8;

        bf16x8 af[2];
        if (AFP32) {
            const float* A = (const float*)Avoid;  // stride IN_CH
            if (k0 < IN_CH) {  // 8-aligned chunks: fully in or fully out
                const float4 a00 = *(const float4*)(A + (size_t)gr0 * IN_CH + k0);
                const float4 a01 = *(const float4*)(A + (size_t)gr0 * IN_CH + k0 + 4);
                const float4 a10 = *(const float4*)(A + (size_t)gr1 * IN_CH + k0);
                const float4 a11 = *(const float4*)(A + (size_t)gr1 * IN_CH + k0 + 4);
                af[0][0] = (short)f2bf(a00.x); af[0][1] = (short)f2bf(a00.y);
                af[0][2] = (short)f2bf(a00.z); af[0][3] = (short)f2bf(a00.w);
                af[0][4] = (short)f2bf(a01.x); af[0][5] = (short)f2bf(a01.y);
                af[0][6] = (short)f2bf(a01.z); af[0][7] = (short)f2bf(a01.w);
                af[1][0] = (short)f2bf(a10.x); af[1][1] = (short)f2bf(a10.y);
                af[1][2] = (short)f2bf(a10.z); af[1][3] = (short)f2bf(a10.w);
                af[1][4] = (short)f2bf(a11.x); af[1][5] = (short)f2bf(a11.y);
                af[1][6] = (short)f2bf(a11.z); af[1][7] = (short)f2bf(a11.w);
            } else {
                af[0] = (bf16x8)0; af[1] = (bf16x8)0;
            }
        } else {
            const unsigned short* A = (const unsigned short*)Avoid;  // stride KPAD
            af[0] = *(const bf16x8*)(A + (size_t)gr0 * KPAD + k0);
            af[1] = *(const bf16x8*)(A + (size_t)gr1 * KPAD + k0);
        }

        const unsigned short* wp = WTP + (((size_t)(k32 * 32 + c16b)) << 9) + lane * 8;
        #pragma unroll
        for (int fn = 0; fn < 8; ++fn) {
            const bf16x8 bg = *(const bf16x8*)(wp + ((size_t)fn << 9));
            acc[0][fn] = __builtin_amdgcn_mfma_f32_16x16x32_bf16(af[0], bg, acc[0][fn], 0, 0, 0);
            acc[1][fn] = __builtin_amdgcn_mfma_f32_16x16x32_bf16(af[1], bg, acc[1][fn], 0, 0, 0);
        }
    }

    // epilogue. C/D layout: col=lane&15, row=(lane>>4)*4+reg  [m89]
    const bool isY = (c0 == 0);
    const int cloc = wc * 128 + (lane & 15);  // 0..255 within tile

    if (isY || ZBF16) {
        constexpr int CST = 264;  // shorts/row: 528B, keeps 16B align
        float bv4[8];
        #pragma unroll
        for (int fn = 0; fn < 8; ++fn)
            bv4[fn] = isY ? 0.f : bias[cloc + fn * 16];
        #pragma unroll
        for (int h = 0; h < 2; ++h) {
            __syncthreads();
            if ((wr >> 1) == h) {
                const int lr0 = (wr & 1) * 32 + (lane >> 4) * 4;
                #pragma unroll
                for (int fm = 0; fm < 2; ++fm)
                    #pragma unroll
                    for (int fn = 0; fn < 8; ++fn)
                        #pragma unroll
                        for (int r = 0; r < 4; ++r)
                            c_lds[(lr0 + fm * 16 + r) * CST + cloc + fn * 16] =
                                (short)f2bf(acc[fm][fn][r] + bv4[fn]);
            }
            __syncthreads();
            const int row = tid >> 3;             // 0..63
            const int cb  = (tid & 7) * 32;       // 0..224
            const int gr  = r0 + h * 64 + row;
            if (gr < M) {
                unsigned short* dst = isY
                    ? (Y + (size_t)gr * 256 + cb)
                    : ((unsigned short*)Z + (size_t)gr * 256 + cb);
                #pragma unroll
                for (int j = 0; j < 4; ++j)
                    *(ushort8*)(dst + j * 8) =
                        *(const ushort8*)&c_lds[row * CST + cb + j * 8];
            }
        }
    } else {
        // Z fp32 direct scalar stores (layer 2; in-place target in d_out)
        const int rbase = r0 + wr * 32 + (lane >> 4) * 4;
        #pragma unroll
        for (int fn = 0; fn < 8; ++fn) {
            const int gc = cloc + fn * 16;
            const float bvv = bias[gc];
            #pragma unroll
            for (int fm = 0; fm < 2; ++fm)
                #pragma unroll
                for (int r = 0; r < 4; ++r) {
                    const int gr = rbase + fm * 16 + r;
                    if (gr < M) ((float*)Z)[(size_t)gr * 256 + gc] = acc[fm][fn][r] + bvv;
                }
        }
    }
}

// ---------------------------------------------------------------------------
// Gather aggregation over bf16 y: out[i] = act( mean_{e}(y[col[e]]) + Z[i] ).
// LAYER1: Z bf16, act=relu, write bf16 h. else: Z fp32, write fp32 d_out.
// ---------------------------------------------------------------------------
template <bool LAYER1>
__global__ void gather_agg_kernel(const unsigned short* __restrict__ Y,
                                  const int* __restrict__ beg_arr,
                                  const int* __restrict__ cnt,
                                  const int* __restrict__ col,
                                  const void* __restrict__ Z,
                                  void* __restrict__ OUT, int N)
{
    const long long gw = ((long long)blockIdx.x * blockDim.x + threadIdx.x) >> 6;
    if (gw >= N) return;
    const int w = (int)gw;
    const int lane = threadIdx.x & 63;
    const int c4 = lane * 4;
    const int beg = beg_arr[w];
    const int deg = cnt[w];
    const int end = beg + deg;

    float4 a0 = make_float4(0.f, 0.f, 0.f, 0.f);
    float4 a1 = make_float4(0.f, 0.f, 0.f, 0.f);
    int e = beg;
    for (; e + 3 < end; e += 4) {
        const int s0 = col[e], s1 = col[e + 1], s2 = col[e + 2], s3 = col[e + 3];
        const ushort4 v0 = *(const ushort4*)(Y + (size_t)s0 * 256 + c4);
        const ushort4 v1 = *(const ushort4*)(Y + (size_t)s1 * 256 + c4);
        const ushort4 v2 = *(const ushort4*)(Y + (size_t)s2 * 256 + c4);
        const ushort4 v3 = *(const ushort4*)(Y + (size_t)s3 * 256 + c4);
        a0.x += bf2f(v0.x) + bf2f(v1.x);  a1.x += bf2f(v2.x) + bf2f(v3.x);
        a0.y += bf2f(v0.y) + bf2f(v1.y);  a1.y += bf2f(v2.y) + bf2f(v3.y);
        a0.z += bf2f(v0.z) + bf2f(v1.z);  a1.z += bf2f(v2.z) + bf2f(v3.z);
        a0.w += bf2f(v0.w) + bf2f(v1.w);  a1.w += bf2f(v2.w) + bf2f(v3.w);
    }
    for (; e < end; ++e) {
        const ushort4 v0 = *(const ushort4*)(Y + (size_t)col[e] * 256 + c4);
        a0.x += bf2f(v0.x); a0.y += bf2f(v0.y);
        a0.z += bf2f(v0.z); a0.w += bf2f(v0.w);
    }
    float4 acc;
    acc.x = a0.x + a1.x; acc.y = a0.y + a1.y;
    acc.z = a0.z + a1.z; acc.w = a0.w + a1.w;

    const float inv = 1.0f / fmaxf((float)deg, 1.0f);
    float4 z;
    if (LAYER1) {
        const ushort4 zb = *(const ushort4*)((const unsigned short*)Z + (size_t)w * 256 + c4);
        z = make_float4(bf2f(zb.x), bf2f(zb.y), bf2f(zb.z), bf2f(zb.w));
    } else {
        z = *(const float4*)((const float*)Z + (size_t)w * 256 + c4);
    }
    float4 o;
    o.x = acc.x * inv + z.x;
    o.y = acc.y * inv + z.y;
    o.z = acc.z * inv + z.z;
    o.w = acc.w * inv + z.w;
    if (LAYER1) {
        o.x = fmaxf(o.x, 0.f); o.y = fmaxf(o.y, 0.f);
        o.z = fmaxf(o.z, 0.f); o.w = fmaxf(o.w, 0.f);
        ushort4 ob;
        ob.x = f2bf(o.x); ob.y = f2bf(o.y); ob.z = f2bf(o.z); ob.w = f2bf(o.w);
        *(ushort4*)((unsigned short*)OUT + (size_t)w * 256 + c4) = ob;
    } else {
        *(float4*)((float*)OUT + (size_t)w * 256 + c4) = o;
    }
}

// ---------------------------------------------------------------------------
extern "C" void kernel_launch(void* const* d_in, const int* in_sizes, int n_in,
                              void* d_out, int out_size, void* d_ws, size_t ws_size,
                              hipStream_t stream) {
    const float* x   = (const float*)d_in[0];
    const void*  ei  = d_in[1];
    const float* W1l = (const float*)d_in[2];
    const float* b1  = (const float*)d_in[3];
    const float* W1r = (const float*)d_in[4];
    const float* W2l = (const float*)d_in[5];
    const float* b2  = (const float*)d_in[6];
    const float* W2r = (const float*)d_in[7];

    const int N = in_sizes[0] / IN_CH;  // 100000
    const int E = in_sizes[1] / 2;      // 1000000

    char* ws = (char*)d_ws;
    size_t off = 0;
    auto alloc = [&](size_t bytes) {
        void* p = ws + off;
        off = (off + bytes + 255) & ~(size_t)255;
        return p;
    };
    int* flag    = (int*)alloc(4);
    int* cnt     = (int*)alloc((size_t)(N + 1) * 4);  // [N] counts + [1] counter
    int* counter = cnt + N;
    int* beg     = (int*)alloc((size_t)N * 4);
    int* cur     = (int*)alloc((size_t)N * 4);
    int* col     = (int*)alloc((size_t)E * 4);
    unsigned short* wtp1 = (unsigned short*)alloc((size_t)10 * 32 * 64 * 8 * 2);  // 320KB
    unsigned short* wtp2 = (unsigned short*)alloc((size_t)8 * 32 * 64 * 8 * 2);   // 256KB
    unsigned short* hb  = (unsigned short*)alloc((size_t)N * 256 * 2);  // h bf16
    unsigned short* y   = (unsigned short*)alloc((size_t)N * 256 * 2);  // y bf16

    float* out = (float*)d_out;
    unsigned short* z1 = (unsigned short*)d_out;  // layer-1 z bf16 scratch in d_out

    // ---- CSR build (by dst, unordered groups) ----
    hipMemsetAsync(cnt, 0, (size_t)(N + 1) * 4, stream);
    detect_idx_kernel<<<1, 64, 0, stream>>>(ei, flag);
    hist_kernel<<<(E + 255) / 256, 256, 0, stream>>>(ei, flag, cnt, E);
    offsets_kernel<<<(N + 255) / 256, 256, 0, stream>>>(cnt, counter, beg, cur, N);
    fill_kernel<<<(E + 255) / 256, 256, 0, stream>>>(ei, flag, cur, col, E);

    // ---- weight packing (fragment-major) ----
    pack_w_kernel<<<(10 * 32 * 64 + 255) / 256, 256, 0, stream>>>(W1l, W1r, wtp1, IN_CH, 320);
    pack_w_kernel<<<(8 * 32 * 64 + 255) / 256, 256, 0, stream>>>(W2l, W2r, wtp2, HID, 256);

    const dim3 ggrid((N + 127) / 128, 2);  // y: 0=Y block, 1=Z block

    // ---- layer 1: y=x@W1l (bf16), z1(d_out,bf16)=x@W1r+b1 ; h=relu(mean+z1) ----
    reg_gemm_kernel<320, true, true><<<ggrid, 512, 0, stream>>>(x, wtp1, b1, y, z1, N);
    gather_agg_kernel<true><<<(N + 3) / 4, 256, 0, stream>>>(y, beg, cnt, col, z1, hb, N);

    // ---- layer 2: y=h@W2l, z(d_out,fp32)=h@W2r+b2 ; out = mean+z ----
    reg_gemm_kernel<256, false, false><<<ggrid, 512, 0, stream>>>(hb, wtp2, b2, y, out, N);
    gather_agg_kernel<false><<<(N + 3) / 4, 256, 0, stream>>>(y, beg, cnt, col, out, out, N);
}

// Round 11
// 555.252 us; speedup vs baseline: 1.0272x; 1.0272x over previous
//
#include <hip/hip_runtime.h>
#include <hip/hip_bf16.h>
#include <cstdint>
#include <cstddef>

#define IN_CH 312
#define HID 256

typedef __attribute__((ext_vector_type(8))) short bf16x8;
typedef __attribute__((ext_vector_type(4))) float f32x4;
typedef __attribute__((ext_vector_type(8))) unsigned short ushort8;

__device__ __forceinline__ unsigned short f2bf(float f) {
    union { float f; unsigned u; } v; v.f = f;
    const unsigned r = v.u + 0x7FFFu + ((v.u >> 16) & 1u);  // RNE
    return (unsigned short)(r >> 16);
}
__device__ __forceinline__ float bf2f(unsigned short s) {
    union { unsigned u; float f; } v; v.u = (unsigned)s << 16;
    return v.f;
}
__device__ __forceinline__ void gload_lds16(const void* g, void* l) {
    __builtin_amdgcn_global_load_lds(
        (const __attribute__((address_space(1))) void*)g,
        (__attribute__((address_space(3))) void*)l, 16, 0, 0);
}

// ---------------------------------------------------------------------------
// Index dtype detector (int64 vs int32 edge_index).
// ---------------------------------------------------------------------------
__global__ void detect_idx_kernel(const void* __restrict__ ei, int* __restrict__ flag) {
    if (blockIdx.x == 0 && threadIdx.x == 0) {
        const int* p = (const int*)ei;
        int ok = 1;
        for (int i = 0; i < 64; ++i) ok &= (p[2 * i + 1] == 0);
        *flag = ok;
    }
}
__device__ __forceinline__ long long load_idx(const void* ei, long long i, bool is64) {
    return is64 ? ((const long long*)ei)[i] : (long long)((const int*)ei)[i];
}

// ---------------------------------------------------------------------------
// CSR build (unordered groups): histogram -> atomic group-offset assignment
// -> atomic-cursor fill. Group placement nondeterministic, membership exact.
// ---------------------------------------------------------------------------
__global__ void hist_kernel(const void* __restrict__ ei, const int* __restrict__ flag,
                            int* __restrict__ cnt, int E) {
    const int i = blockIdx.x * blockDim.x + threadIdx.x;
    if (i >= E) return;
    const bool is64 = (*flag != 0);
    atomicAdd(&cnt[load_idx(ei, (long long)E + i, is64)], 1);
}

__global__ void offsets_kernel(const int* __restrict__ cnt, int* __restrict__ counter,
                               int* __restrict__ beg, int* __restrict__ cur, int n) {
    const int i = blockIdx.x * blockDim.x + threadIdx.x;
    if (i >= n) return;
    const int b = atomicAdd(counter, cnt[i]);
    beg[i] = b;
    cur[i] = b;
}

__global__ void fill_kernel(const void* __restrict__ ei, const int* __restrict__ flag,
                            int* __restrict__ cur, int* __restrict__ col, int E) {
    const int i = blockIdx.x * blockDim.x + threadIdx.x;
    if (i >= E) return;
    const bool is64 = (*flag != 0);
    const long long s = load_idx(ei, i, is64);
    const long long d = load_idx(ei, (long long)E + i, is64);
    col[atomicAdd(&cur[d], 1)] = (int)s;
}

// ---------------------------------------------------------------------------
// Pack [Wl|Wr] into MFMA B-fragment order (proven R10):
//   frag fi = k32*32 + c16 (c16 = col/16, k32 = k/32), slot = lane, 8 bf16.
// A wave's bg load becomes ONE fully-coalesced 1KB read: base + lane*16B.
// ---------------------------------------------------------------------------
__global__ void pack_w_kernel(const float* __restrict__ Wl, const float* __restrict__ Wr,
                              unsigned short* __restrict__ wtp, int K, int Kpad) {
    const int tid = blockIdx.x * blockDim.x + threadIdx.x;
    const int total = (Kpad / 32) * 32 * 64;
    if (tid >= total) return;
    const int k32 = tid >> 11;           // /(32*64)
    const int rem = tid & 2047;
    const int c16 = rem >> 6;
    const int l   = rem & 63;
    const int col = c16 * 16 + (l & 15);
    const int kbase = k32 * 32 + (l >> 4) * 8;
    ushort8 o;
    #pragma unroll
    for (int j = 0; j < 8; ++j) {
        const int k = kbase + j;
        float v = 0.f;
        if (k < K) v = (col < 256) ? Wl[(size_t)k * 256 + col]
                                   : Wr[(size_t)k * 256 + (col - 256)];
        o[j] = f2bf(v);
    }
    *(ushort8*)(wtp + (size_t)tid * 8) = o;
}

// ---------------------------------------------------------------------------
// Hybrid MFMA GEMM (R11): A staged in LDS (16KB, single buffer, the barrier
// drain covers ONLY A's 2 gloads/wave); B read per-fragment from L2-resident
// packed W (plain register loads, never block the barrier, overlap MFMA).
// Tile 128x256 (8 waves, 4x2, wave-tile 32x128), BK=64, grid (M/128, 2):
// y=0 -> Y cols 0-255, y=1 -> Z cols 256-511. NO VGPR cap (R10's spill bug).
//   AFP32: A fp32 [M][312] reg-staged (float4 -> cvt -> swizzled ds_write).
//   else   A bf16 [M][KPAD] via global_load_lds (pre-swizzled source).
// Epilogue (proven): bf16 via LDS transpose (c_lds shares smem with a_lds)
// -> ushort8 coalesced stores; layer-2 Z fp32 scalar in-place.
// ---------------------------------------------------------------------------
template <int KPAD, bool AFP32, bool ZBF16>
__global__ __launch_bounds__(512) void mfma_gemm_kernel(
    const void* __restrict__ Avoid,          // [M][312] f32 or [M][KPAD] bf16
    const unsigned short* __restrict__ WTP,  // packed B fragments
    const float* __restrict__ bias,          // [256]
    unsigned short* __restrict__ Y,          // [M][256] bf16
    void* __restrict__ Z,                    // [M][256] bf16 or fp32
    int M)
{
    __shared__ __align__(16) char smem[64 * 264 * 2];  // 33KB: a_lds / c_lds share
    short* a_lds = (short*)smem;                       // [128*64] bf16 (16 KB)

    const int tid  = (int)threadIdx.x;
    const int lane = tid & 63;
    const int wid  = tid >> 6;              // 0..7
    const int wr = wid >> 1, wc = wid & 1;  // 4 wave-rows x 2 wave-cols
    const int r0 = blockIdx.x * 128;
    const int c0 = blockIdx.y * 256;        // 0 -> Y, 256 -> Z

    const int lrow = lane & 15;
    const int kgrp = lane >> 4;             // 0..3

    f32x4 acc[2][8];
    #pragma unroll
    for (int i = 0; i < 2; ++i)
        #pragma unroll
        for (int j = 0; j < 8; ++j) acc[i][j] = (f32x4)0.f;

    // gload staging geometry: wave-load ld covers tile rows ld*8..ld*8+7;
    // lane l -> row ld*8 + (l>>3), source 16B chunk (l&7) ^ (l>>3).
    const int ldrow  = lane >> 3;
    const int schunk = (lane & 7) ^ ldrow;

    const int c16b = (c0 >> 4) + wc * 8;  // global 16-col fragment base

    for (int kb = 0; kb < KPAD; kb += 64) {
        __syncthreads();  // readers of a_lds done
        // ---- stage A tile: 128 rows x 128B (16 KB) ----
        if (AFP32) {
            const float* A = (const float*)Avoid;  // stride IN_CH
            float4 v[4];
            #pragma unroll
            for (int it = 0; it < 4; ++it) {
                const int idx = tid + it * 512;
                const int row = idx >> 4, q = idx & 15;
                const int gr = min(r0 + row, M - 1);
                const int gk = kb + q * 4;  // quad-aligned; IN_CH%4==0
                v[it] = (gk < IN_CH) ? *(const float4*)(A + (size_t)gr * IN_CH + gk)
                                     : make_float4(0.f, 0.f, 0.f, 0.f);
            }
            #pragma unroll
            for (int it = 0; it < 4; ++it) {
                const int idx = tid + it * 512;
                const int row = idx >> 4, q = idx & 15;
                ushort4 b4;
                b4.x = f2bf(v[it].x); b4.y = f2bf(v[it].y);
                b4.z = f2bf(v[it].z); b4.w = f2bf(v[it].w);
                const int byte = row * 128 + (((q >> 1) ^ (row & 7)) * 16) + (q & 1) * 8;
                *(ushort4*)((char*)a_lds + byte) = b4;
            }
        } else {
            const unsigned short* A = (const unsigned short*)Avoid;  // stride KPAD
            #pragma unroll
            for (int j = 0; j < 2; ++j) {
                const int ld = wid * 2 + j;
                const int trow = ld * 8 + ldrow;
                const int gr = min(r0 + trow, M - 1);
                gload_lds16(A + (size_t)gr * KPAD + kb + schunk * 8,
                            (char*)a_lds + ld * 1024);
            }
        }
        __syncthreads();  // drains only A staging

        #pragma unroll
        for (int ks = 0; ks < 2; ++ks) {
            bf16x8 af[2];
            #pragma unroll
            for (int f = 0; f < 2; ++f) {
                const int arow = wr * 32 + f * 16 + lrow;
                const int ach  = (ks * 4 + kgrp) ^ (arow & 7);
                af[f] = *(const bf16x8*)((const char*)a_lds + arow * 128 + ach * 16);
            }
            // B fragments straight from L2-resident packed W (no barrier dep)
            const unsigned short* wp =
                WTP + (((size_t)(((kb >> 5) + ks) * 32 + c16b)) << 9) + lane * 8;
            #pragma unroll
            for (int fn = 0; fn < 8; ++fn) {
                const bf16x8 bg = *(const bf16x8*)(wp + ((size_t)fn << 9));
                acc[0][fn] = __builtin_amdgcn_mfma_f32_16x16x32_bf16(af[0], bg, acc[0][fn], 0, 0, 0);
                acc[1][fn] = __builtin_amdgcn_mfma_f32_16x16x32_bf16(af[1], bg, acc[1][fn], 0, 0, 0);
            }
        }
    }

    // epilogue. C/D layout: col=lane&15, row=(lane>>4)*4+reg  [m89]
    const bool isY = (c0 == 0);
    const int cloc = wc * 128 + (lane & 15);  // 0..255 within tile

    if (isY || ZBF16) {
        constexpr int CST = 264;  // shorts/row: 528B, keeps 16B align
        short* c_lds = (short*)smem;
        float bv4[8];
        #pragma unroll
        for (int fn = 0; fn < 8; ++fn)
            bv4[fn] = isY ? 0.f : bias[cloc + fn * 16];
        #pragma unroll
        for (int h = 0; h < 2; ++h) {
            __syncthreads();
            if ((wr >> 1) == h) {
                const int lr0 = (wr & 1) * 32 + (lane >> 4) * 4;
                #pragma unroll
                for (int fm = 0; fm < 2; ++fm)
                    #pragma unroll
                    for (int fn = 0; fn < 8; ++fn)
                        #pragma unroll
                        for (int r = 0; r < 4; ++r)
                            c_lds[(lr0 + fm * 16 + r) * CST + cloc + fn * 16] =
                                (short)f2bf(acc[fm][fn][r] + bv4[fn]);
            }
            __syncthreads();
            const int row = tid >> 3;             // 0..63
            const int cb  = (tid & 7) * 32;       // 0..224
            const int gr  = r0 + h * 64 + row;
            if (gr < M) {
                unsigned short* dst = isY
                    ? (Y + (size_t)gr * 256 + cb)
                    : ((unsigned short*)Z + (size_t)gr * 256 + cb);
                #pragma unroll
                for (int j = 0; j < 4; ++j)
                    *(ushort8*)(dst + j * 8) =
                        *(const ushort8*)&c_lds[row * CST + cb + j * 8];
            }
        }
    } else {
        // Z fp32 direct scalar stores (layer 2; in-place target in d_out)
        const int rbase = r0 + wr * 32 + (lane >> 4) * 4;
        #pragma unroll
        for (int fn = 0; fn < 8; ++fn) {
            const int gc = cloc + fn * 16;
            const float bvv = bias[gc];
            #pragma unroll
            for (int fm = 0; fm < 2; ++fm)
                #pragma unroll
                for (int r = 0; r < 4; ++r) {
                    const int gr = rbase + fm * 16 + r;
                    if (gr < M) ((float*)Z)[(size_t)gr * 256 + gc] = acc[fm][fn][r] + bvv;
                }
        }
    }
}

// ---------------------------------------------------------------------------
// Gather aggregation over bf16 y: out[i] = act( mean_{e}(y[col[e]]) + Z[i] ).
// LAYER1: Z bf16, act=relu, write bf16 h. else: Z fp32, write fp32 d_out.
// ---------------------------------------------------------------------------
template <bool LAYER1>
__global__ void gather_agg_kernel(const unsigned short* __restrict__ Y,
                                  const int* __restrict__ beg_arr,
                                  const int* __restrict__ cnt,
                                  const int* __restrict__ col,
                                  const void* __restrict__ Z,
                                  void* __restrict__ OUT, int N)
{
    const long long gw = ((long long)blockIdx.x * blockDim.x + threadIdx.x) >> 6;
    if (gw >= N) return;
    const int w = (int)gw;
    const int lane = threadIdx.x & 63;
    const int c4 = lane * 4;
    const int beg = beg_arr[w];
    const int deg = cnt[w];
    const int end = beg + deg;

    float4 a0 = make_float4(0.f, 0.f, 0.f, 0.f);
    float4 a1 = make_float4(0.f, 0.f, 0.f, 0.f);
    int e = beg;
    for (; e + 3 < end; e += 4) {
        const int s0 = col[e], s1 = col[e + 1], s2 = col[e + 2], s3 = col[e + 3];
        const ushort4 v0 = *(const ushort4*)(Y + (size_t)s0 * 256 + c4);
        const ushort4 v1 = *(const ushort4*)(Y + (size_t)s1 * 256 + c4);
        const ushort4 v2 = *(const ushort4*)(Y + (size_t)s2 * 256 + c4);
        const ushort4 v3 = *(const ushort4*)(Y + (size_t)s3 * 256 + c4);
        a0.x += bf2f(v0.x) + bf2f(v1.x);  a1.x += bf2f(v2.x) + bf2f(v3.x);
        a0.y += bf2f(v0.y) + bf2f(v1.y);  a1.y += bf2f(v2.y) + bf2f(v3.y);
        a0.z += bf2f(v0.z) + bf2f(v1.z);  a1.z += bf2f(v2.z) + bf2f(v3.z);
        a0.w += bf2f(v0.w) + bf2f(v1.w);  a1.w += bf2f(v2.w) + bf2f(v3.w);
    }
    for (; e < end; ++e) {
        const ushort4 v0 = *(const ushort4*)(Y + (size_t)col[e] * 256 + c4);
        a0.x += bf2f(v0.x); a0.y += bf2f(v0.y);
        a0.z += bf2f(v0.z); a0.w += bf2f(v0.w);
    }
    float4 acc;
    acc.x = a0.x + a1.x; acc.y = a0.y + a1.y;
    acc.z = a0.z + a1.z; acc.w = a0.w + a1.w;

    const float inv = 1.0f / fmaxf((float)deg, 1.0f);
    float4 z;
    if (LAYER1) {
        const ushort4 zb = *(const ushort4*)((const unsigned short*)Z + (size_t)w * 256 + c4);
        z = make_float4(bf2f(zb.x), bf2f(zb.y), bf2f(zb.z), bf2f(zb.w));
    } else {
        z = *(const float4*)((const float*)Z + (size_t)w * 256 + c4);
    }
    float4 o;
    o.x = acc.x * inv + z.x;
    o.y = acc.y * inv + z.y;
    o.z = acc.z * inv + z.z;
    o.w = acc.w * inv + z.w;
    if (LAYER1) {
        o.x = fmaxf(o.x, 0.f); o.y = fmaxf(o.y, 0.f);
        o.z = fmaxf(o.z, 0.f); o.w = fmaxf(o.w, 0.f);
        ushort4 ob;
        ob.x = f2bf(o.x); ob.y = f2bf(o.y); ob.z = f2bf(o.z); ob.w = f2bf(o.w);
        *(ushort4*)((unsigned short*)OUT + (size_t)w * 256 + c4) = ob;
    } else {
        *(float4*)((float*)OUT + (size_t)w * 256 + c4) = o;
    }
}

// ---------------------------------------------------------------------------
extern "C" void kernel_launch(void* const* d_in, const int* in_sizes, int n_in,
                              void* d_out, int out_size, void* d_ws, size_t ws_size,
                              hipStream_t stream) {
    const float* x   = (const float*)d_in[0];
    const void*  ei  = d_in[1];
    const float* W1l = (const float*)d_in[2];
    const float* b1  = (const float*)d_in[3];
    const float* W1r = (const float*)d_in[4];
    const float* W2l = (const float*)d_in[5];
    const float* b2  = (const float*)d_in[6];
    const float* W2r = (const float*)d_in[7];

    const int N = in_sizes[0] / IN_CH;  // 100000
    const int E = in_sizes[1] / 2;      // 1000000

    char* ws = (char*)d_ws;
    size_t off = 0;
    auto alloc = [&](size_t bytes) {
        void* p = ws + off;
        off = (off + bytes + 255) & ~(size_t)255;
        return p;
    };
    int* flag    = (int*)alloc(4);
    int* cnt     = (int*)alloc((size_t)(N + 1) * 4);  // [N] counts + [1] counter
    int* counter = cnt + N;
    int* beg     = (int*)alloc((size_t)N * 4);
    int* cur     = (int*)alloc((size_t)N * 4);
    int* col     = (int*)alloc((size_t)E * 4);
    unsigned short* wtp1 = (unsigned short*)alloc((size_t)10 * 32 * 64 * 8 * 2);  // 320KB
    unsigned short* wtp2 = (unsigned short*)alloc((size_t)8 * 32 * 64 * 8 * 2);   // 256KB
    unsigned short* hb  = (unsigned short*)alloc((size_t)N * 256 * 2);  // h bf16
    unsigned short* y   = (unsigned short*)alloc((size_t)N * 256 * 2);  // y bf16

    float* out = (float*)d_out;
    unsigned short* z1 = (unsigned short*)d_out;  // layer-1 z bf16 scratch in d_out

    // ---- CSR build (by dst, unordered groups) ----
    hipMemsetAsync(cnt, 0, (size_t)(N + 1) * 4, stream);
    detect_idx_kernel<<<1, 64, 0, stream>>>(ei, flag);
    hist_kernel<<<(E + 255) / 256, 256, 0, stream>>>(ei, flag, cnt, E);
    offsets_kernel<<<(N + 255) / 256, 256, 0, stream>>>(cnt, counter, beg, cur, N);
    fill_kernel<<<(E + 255) / 256, 256, 0, stream>>>(ei, flag, cur, col, E);

    // ---- weight packing (fragment-major) ----
    pack_w_kernel<<<(10 * 32 * 64 + 255) / 256, 256, 0, stream>>>(W1l, W1r, wtp1, IN_CH, 320);
    pack_w_kernel<<<(8 * 32 * 64 + 255) / 256, 256, 0, stream>>>(W2l, W2r, wtp2, HID, 256);

    const dim3 ggrid((N + 127) / 128, 2);  // y: 0=Y block, 1=Z block

    // ---- layer 1: y=x@W1l (bf16), z1(d_out,bf16)=x@W1r+b1 ; h=relu(mean+z1) ----
    mfma_gemm_kernel<320, true, true><<<ggrid, 512, 0, stream>>>(x, wtp1, b1, y, z1, N);
    gather_agg_kernel<true><<<(N + 3) / 4, 256, 0, stream>>>(y, beg, cnt, col, z1, hb, N);

    // ---- layer 2: y=h@W2l, z(d_out,fp32)=h@W2r+b2 ; out = mean+z ----
    mfma_gemm_kernel<256, false, false><<<ggrid, 512, 0, stream>>>(hb, wtp2, b2, y, out, N);
    gather_agg_kernel<false><<<(N + 3) / 4, 256, 0, stream>>>(y, beg, cnt, col, out, out, N);
}

// Round 12
// 480.240 us; speedup vs baseline: 1.1876x; 1.1562x over previous
//
#include <hip/hip_runtime.h>
#include <hip/hip_bf16.h>
#include <cstdint>
#include <cstddef>

#define IN_CH 312
#define HID 256

typedef __attribute__((ext_vector_type(8))) short bf16x8;
typedef __attribute__((ext_vector_type(4))) float f32x4;
typedef __attribute__((ext_vector_type(8))) unsigned short ushort8;

__device__ __forceinline__ unsigned short f2bf(float f) {
    union { float f; unsigned u; } v; v.f = f;
    const unsigned r = v.u + 0x7FFFu + ((v.u >> 16) & 1u);  // RNE
    return (unsigned short)(r >> 16);
}
__device__ __forceinline__ float bf2f(unsigned short s) {
    union { unsigned u; float f; } v; v.u = (unsigned)s << 16;
    return v.f;
}
__device__ __forceinline__ void gload_lds16(const void* g, void* l) {
    __builtin_amdgcn_global_load_lds(
        (const __attribute__((address_space(1))) void*)g,
        (__attribute__((address_space(3))) void*)l, 16, 0, 0);
}

// ---------------------------------------------------------------------------
// Index dtype detector (int64 vs int32 edge_index).
// ---------------------------------------------------------------------------
__global__ void detect_idx_kernel(const void* __restrict__ ei, int* __restrict__ flag) {
    if (blockIdx.x == 0 && threadIdx.x == 0) {
        const int* p = (const int*)ei;
        int ok = 1;
        for (int i = 0; i < 64; ++i) ok &= (p[2 * i + 1] == 0);
        *flag = ok;
    }
}
__device__ __forceinline__ long long load_idx(const void* ei, long long i, bool is64) {
    return is64 ? ((const long long*)ei)[i] : (long long)((const int*)ei)[i];
}

// ---------------------------------------------------------------------------
// CSR build (unordered groups): histogram -> atomic group-offset assignment
// -> atomic-cursor fill. Group placement nondeterministic, membership exact.
// ---------------------------------------------------------------------------
__global__ void hist_kernel(const void* __restrict__ ei, const int* __restrict__ flag,
                            int* __restrict__ cnt, int E) {
    const int i = blockIdx.x * blockDim.x + threadIdx.x;
    if (i >= E) return;
    const bool is64 = (*flag != 0);
    atomicAdd(&cnt[load_idx(ei, (long long)E + i, is64)], 1);
}

__global__ void offsets_kernel(const int* __restrict__ cnt, int* __restrict__ counter,
                               int* __restrict__ beg, int* __restrict__ cur, int n) {
    const int i = blockIdx.x * blockDim.x + threadIdx.x;
    if (i >= n) return;
    const int b = atomicAdd(counter, cnt[i]);
    beg[i] = b;
    cur[i] = b;
}

__global__ void fill_kernel(const void* __restrict__ ei, const int* __restrict__ flag,
                            int* __restrict__ cur, int* __restrict__ col, int E) {
    const int i = blockIdx.x * blockDim.x + threadIdx.x;
    if (i >= E) return;
    const bool is64 = (*flag != 0);
    const long long s = load_idx(ei, i, is64);
    const long long d = load_idx(ei, (long long)E + i, is64);
    col[atomicAdd(&cur[d], 1)] = (int)s;
}

// WcatT[c][k] = (c<256 ? Wl[k][c] : Wr[k][c-256]), bf16, k >= K zero-padded.
__global__ void convert_w_kernel(const float* __restrict__ Wl, const float* __restrict__ Wr,
                                 unsigned short* __restrict__ wt, int K, int Kpad) {
    const int tid = blockIdx.x * blockDim.x + threadIdx.x;
    if (tid >= 512 * Kpad) return;
    const int c = tid / Kpad;
    const int k = tid % Kpad;
    float v = 0.f;
    if (k < K) v = (c < 256) ? Wl[(size_t)k * 256 + c] : Wr[(size_t)k * 256 + (c - 256)];
    wt[(size_t)c * Kpad + k] = f2bf(v);
}

// ---------------------------------------------------------------------------
// 2-phase double-buffered MFMA GEMM (T3 recipe): per step, STAGE(t+1) into
// buf^1 is issued BEFORE compute(t); one vmcnt-draining barrier per step ->
// next tile's loads are in flight during the whole compute phase (fixes the
// R9 stage->drain->compute latency stall: 135us @1.78TB/s, MfmaUtil 9.6).
// Tile 128x256, BK=32, 8 waves (4x2), wave-tile 32x128. LDS 48KB (A 2x8KB +
// B 2x16KB; epilogue c_lds overlaps) -> 3 blocks/CU. Grid (M/128, 2).
//   AFP32: A fp32 [M][312]: T14 split - float4 loads issued early, cvt +
//          swizzled ds_write after compute. Else bf16 via global_load_lds
//          (linear dest + pre-swizzled source; rule #21).
// LDS rows are 64B = 4 chunks; XOR swizzle chunk c ^= (row&3) both sides.
// Epilogue (proven R9): bf16 via LDS transpose -> ushort8; Z fp32 scalar.
// ---------------------------------------------------------------------------
template <int KPAD, bool AFP32, bool ZBF16>
__global__ __launch_bounds__(512) void mfma_gemm_kernel(
    const void* __restrict__ Avoid,         // [M][312] f32 or [M][KPAD] bf16
    const unsigned short* __restrict__ WT,  // [512][KPAD] bf16
    const float* __restrict__ bias,         // [256]
    unsigned short* __restrict__ Y,         // [M][256] bf16
    void* __restrict__ Z,                   // [M][256] bf16 or fp32
    int M)
{
    constexpr int NS = KPAD / 32;  // K-steps
    __shared__ __align__(16) char smem[49152];
    // abuf[b] = smem + b*8192 (128 rows x 64B); bbuf[b] = smem+16384+b*16384
    // (256 rows x 64B). c_lds (33KB) overlaps from smem base in epilogue.

    const int tid  = (int)threadIdx.x;
    const int lane = tid & 63;
    const int wid  = tid >> 6;              // 0..7
    const int wr = wid >> 1, wc = wid & 1;  // 4 wave-rows x 2 wave-cols
    const int r0 = blockIdx.x * 128;
    const int c0 = blockIdx.y * 256;        // 0 -> Y, 256 -> Z

    const int lrow = lane & 15;
    const int kgrp = lane >> 4;             // 0..3 (logical 16B chunk)

    f32x4 acc[2][8];
    #pragma unroll
    for (int i = 0; i < 2; ++i)
        #pragma unroll
        for (int j = 0; j < 8; ++j) acc[i][j] = (f32x4)0.f;

    // gload geometry: wave-load = 1KB = 16 rows x 64B.
    // lane l -> row_in_ld = l>>2, logical chunk c = (l&3) ^ ((l>>2)&3).
    const int glrow = lane >> 2;
    const int glc   = (lane & 3) ^ (glrow & 3);

    // reg-staging geometry (AFP32): tid -> row = tid>>2, chunk c = tid&3.
    const int srow = tid >> 2;
    const int sc   = tid & 3;
    const int sgr  = min(r0 + srow, M - 1);
    const int swbyte = srow * 64 + ((sc ^ (srow & 3)) * 16);

    // ---- staging helpers ----
    auto stageB = [&](int t, int b) {
        char* bb = smem + 16384 + b * 16384;
        const int kb = t * 32;
        #pragma unroll
        for (int j = 0; j < 2; ++j) {
            const int ld = wid * 2 + j;
            const int row = ld * 16 + glrow;
            gload_lds16(WT + (size_t)(c0 + row) * KPAD + kb + glc * 8,
                        bb + ld * 1024);
        }
    };
    auto stageA_g = [&](int t, int b) {  // bf16 A via global_load_lds
        char* ab = smem + b * 8192;
        const unsigned short* A = (const unsigned short*)Avoid;
        const int row = wid * 16 + glrow;
        const int gr = min(r0 + row, M - 1);
        gload_lds16(A + (size_t)gr * KPAD + t * 32 + glc * 8, ab + wid * 1024);
    };
    float4 va, vb;  // in-flight fp32 A chunk (AFP32 path)
    auto loadA_r = [&](int t) {
        const float* A = (const float*)Avoid;
        const int gk = t * 32 + sc * 8;
        if (gk < IN_CH) {  // 8-chunks align with 312
            va = *(const float4*)(A + (size_t)sgr * IN_CH + gk);
            vb = *(const float4*)(A + (size_t)sgr * IN_CH + gk + 4);
        } else {
            va = make_float4(0.f, 0.f, 0.f, 0.f);
            vb = make_float4(0.f, 0.f, 0.f, 0.f);
        }
    };
    auto writeA = [&](int b) {
        ushort8 o;
        o[0] = f2bf(va.x); o[1] = f2bf(va.y); o[2] = f2bf(va.z); o[3] = f2bf(va.w);
        o[4] = f2bf(vb.x); o[5] = f2bf(vb.y); o[6] = f2bf(vb.z); o[7] = f2bf(vb.w);
        *(ushort8*)(smem + b * 8192 + swbyte) = o;
    };
    auto compute = [&](int b) {
        const char* ab = smem + b * 8192;
        const char* bb = smem + 16384 + b * 16384;
        bf16x8 af[2], bg[8];
        #pragma unroll
        for (int f = 0; f < 2; ++f) {
            const int arow = wr * 32 + f * 16 + lrow;
            const int p = kgrp ^ (arow & 3);
            af[f] = *(const bf16x8*)(ab + arow * 64 + p * 16);
        }
        #pragma unroll
        for (int fn = 0; fn < 8; ++fn) {
            const int brow = wc * 128 + fn * 16 + lrow;
            const int p = kgrp ^ (brow & 3);
            bg[fn] = *(const bf16x8*)(bb + brow * 64 + p * 16);
        }
        #pragma unroll
        for (int fn = 0; fn < 8; ++fn) {
            acc[0][fn] = __builtin_amdgcn_mfma_f32_16x16x32_bf16(af[0], bg[fn], acc[0][fn], 0, 0, 0);
            acc[1][fn] = __builtin_amdgcn_mfma_f32_16x16x32_bf16(af[1], bg[fn], acc[1][fn], 0, 0, 0);
        }
    };

    // ---- prologue: stage tile 0 into buf 0 ----
    stageB(0, 0);
    if (AFP32) { loadA_r(0); writeA(0); }
    else       { stageA_g(0, 0); }
    __syncthreads();  // drains vmcnt + lgkm

    // ---- 2-phase main loop ----
    for (int t = 0; t < NS; ++t) {
        const int b = t & 1, nb = b ^ 1;
        if (t + 1 < NS) {
            stageB(t + 1, nb);                    // loads fly during compute
            if (AFP32) loadA_r(t + 1);
            else       stageA_g(t + 1, nb);
        }
        compute(b);
        if (AFP32 && t + 1 < NS) writeA(nb);      // after MFMAs, before barrier
        __syncthreads();                          // vmcnt(0) drain + barrier
    }

    // epilogue. C/D layout: col=lane&15, row=(lane>>4)*4+reg  [m89]
    const bool isY = (c0 == 0);
    const int cloc = wc * 128 + (lane & 15);  // 0..255 within tile

    if (isY || ZBF16) {
        constexpr int CST = 264;  // shorts/row: 528B, keeps 16B align
        short* c_lds = (short*)smem;
        float bv4[8];
        #pragma unroll
        for (int fn = 0; fn < 8; ++fn)
            bv4[fn] = isY ? 0.f : bias[cloc + fn * 16];
        #pragma unroll
        for (int h = 0; h < 2; ++h) {
            __syncthreads();
            if ((wr >> 1) == h) {
                const int lr0 = (wr & 1) * 32 + (lane >> 4) * 4;
                #pragma unroll
                for (int fm = 0; fm < 2; ++fm)
                    #pragma unroll
                    for (int fn = 0; fn < 8; ++fn)
                        #pragma unroll
                        for (int r = 0; r < 4; ++r)
                            c_lds[(lr0 + fm * 16 + r) * CST + cloc + fn * 16] =
                                (short)f2bf(acc[fm][fn][r] + bv4[fn]);
            }
            __syncthreads();
            const int row = tid >> 3;             // 0..63
            const int cb  = (tid & 7) * 32;       // 0..224
            const int gr  = r0 + h * 64 + row;
            if (gr < M) {
                unsigned short* dst = isY
                    ? (Y + (size_t)gr * 256 + cb)
                    : ((unsigned short*)Z + (size_t)gr * 256 + cb);
                #pragma unroll
                for (int j = 0; j < 4; ++j)
                    *(ushort8*)(dst + j * 8) =
                        *(const ushort8*)&c_lds[row * CST + cb + j * 8];
            }
        }
    } else {
        // Z fp32 direct scalar stores (layer 2; in-place target in d_out)
        const int rbase = r0 + wr * 32 + (lane >> 4) * 4;
        #pragma unroll
        for (int fn = 0; fn < 8; ++fn) {
            const int gc = cloc + fn * 16;
            const float bvv = bias[gc];
            #pragma unroll
            for (int fm = 0; fm < 2; ++fm)
                #pragma unroll
                for (int r = 0; r < 4; ++r) {
                    const int gr = rbase + fm * 16 + r;
                    if (gr < M) ((float*)Z)[(size_t)gr * 256 + gc] = acc[fm][fn][r] + bvv;
                }
        }
    }
}

// ---------------------------------------------------------------------------
// Gather aggregation over bf16 y: out[i] = act( mean_{e}(y[col[e]]) + Z[i] ).
// LAYER1: Z bf16, act=relu, write bf16 h. else: Z fp32, write fp32 d_out.
// ---------------------------------------------------------------------------
template <bool LAYER1>
__global__ void gather_agg_kernel(const unsigned short* __restrict__ Y,
                                  const int* __restrict__ beg_arr,
                                  const int* __restrict__ cnt,
                                  const int* __restrict__ col,
                                  const void* __restrict__ Z,
                                  void* __restrict__ OUT, int N)
{
    const long long gw = ((long long)blockIdx.x * blockDim.x + threadIdx.x) >> 6;
    if (gw >= N) return;
    const int w = (int)gw;
    const int lane = threadIdx.x & 63;
    const int c4 = lane * 4;
    const int beg = beg_arr[w];
    const int deg = cnt[w];
    const int end = beg + deg;

    float4 a0 = make_float4(0.f, 0.f, 0.f, 0.f);
    float4 a1 = make_float4(0.f, 0.f, 0.f, 0.f);
    int e = beg;
    for (; e + 3 < end; e += 4) {
        const int s0 = col[e], s1 = col[e + 1], s2 = col[e + 2], s3 = col[e + 3];
        const ushort4 v0 = *(const ushort4*)(Y + (size_t)s0 * 256 + c4);
        const ushort4 v1 = *(const ushort4*)(Y + (size_t)s1 * 256 + c4);
        const ushort4 v2 = *(const ushort4*)(Y + (size_t)s2 * 256 + c4);
        const ushort4 v3 = *(const ushort4*)(Y + (size_t)s3 * 256 + c4);
        a0.x += bf2f(v0.x) + bf2f(v1.x);  a1.x += bf2f(v2.x) + bf2f(v3.x);
        a0.y += bf2f(v0.y) + bf2f(v1.y);  a1.y += bf2f(v2.y) + bf2f(v3.y);
        a0.z += bf2f(v0.z) + bf2f(v1.z);  a1.z += bf2f(v2.z) + bf2f(v3.z);
        a0.w += bf2f(v0.w) + bf2f(v1.w);  a1.w += bf2f(v2.w) + bf2f(v3.w);
    }
    for (; e < end; ++e) {
        const ushort4 v0 = *(const ushort4*)(Y + (size_t)col[e] * 256 + c4);
        a0.x += bf2f(v0.x); a0.y += bf2f(v0.y);
        a0.z += bf2f(v0.z); a0.w += bf2f(v0.w);
    }
    float4 acc;
    acc.x = a0.x + a1.x; acc.y = a0.y + a1.y;
    acc.z = a0.z + a1.z; acc.w = a0.w + a1.w;

    const float inv = 1.0f / fmaxf((float)deg, 1.0f);
    float4 z;
    if (LAYER1) {
        const ushort4 zb = *(const ushort4*)((const unsigned short*)Z + (size_t)w * 256 + c4);
        z = make_float4(bf2f(zb.x), bf2f(zb.y), bf2f(zb.z), bf2f(zb.w));
    } else {
        z = *(const float4*)((const float*)Z + (size_t)w * 256 + c4);
    }
    float4 o;
    o.x = acc.x * inv + z.x;
    o.y = acc.y * inv + z.y;
    o.z = acc.z * inv + z.z;
    o.w = acc.w * inv + z.w;
    if (LAYER1) {
        o.x = fmaxf(o.x, 0.f); o.y = fmaxf(o.y, 0.f);
        o.z = fmaxf(o.z, 0.f); o.w = fmaxf(o.w, 0.f);
        ushort4 ob;
        ob.x = f2bf(o.x); ob.y = f2bf(o.y); ob.z = f2bf(o.z); ob.w = f2bf(o.w);
        *(ushort4*)((unsigned short*)OUT + (size_t)w * 256 + c4) = ob;
    } else {
        *(float4*)((float*)OUT + (size_t)w * 256 + c4) = o;
    }
}

// ---------------------------------------------------------------------------
extern "C" void kernel_launch(void* const* d_in, const int* in_sizes, int n_in,
                              void* d_out, int out_size, void* d_ws, size_t ws_size,
                              hipStream_t stream) {
    const float* x   = (const float*)d_in[0];
    const void*  ei  = d_in[1];
    const float* W1l = (const float*)d_in[2];
    const float* b1  = (const float*)d_in[3];
    const float* W1r = (const float*)d_in[4];
    const float* W2l = (const float*)d_in[5];
    const float* b2  = (const float*)d_in[6];
    const float* W2r = (const float*)d_in[7];

    const int N = in_sizes[0] / IN_CH;  // 100000
    const int E = in_sizes[1] / 2;      // 1000000

    char* ws = (char*)d_ws;
    size_t off = 0;
    auto alloc = [&](size_t bytes) {
        void* p = ws + off;
        off = (off + bytes + 255) & ~(size_t)255;
        return p;
    };
    int* flag    = (int*)alloc(4);
    int* cnt     = (int*)alloc((size_t)(N + 1) * 4);  // [N] counts + [1] counter
    int* counter = cnt + N;
    int* beg     = (int*)alloc((size_t)N * 4);
    int* cur     = (int*)alloc((size_t)N * 4);
    int* col     = (int*)alloc((size_t)E * 4);
    unsigned short* wt1 = (unsigned short*)alloc((size_t)512 * 320 * 2);
    unsigned short* wt2 = (unsigned short*)alloc((size_t)512 * 256 * 2);
    unsigned short* hb  = (unsigned short*)alloc((size_t)N * 256 * 2);  // h bf16
    unsigned short* y   = (unsigned short*)alloc((size_t)N * 256 * 2);  // y bf16

    float* out = (float*)d_out;
    unsigned short* z1 = (unsigned short*)d_out;  // layer-1 z bf16 scratch in d_out

    // ---- CSR build (by dst, unordered groups) ----
    hipMemsetAsync(cnt, 0, (size_t)(N + 1) * 4, stream);
    detect_idx_kernel<<<1, 64, 0, stream>>>(ei, flag);
    hist_kernel<<<(E + 255) / 256, 256, 0, stream>>>(ei, flag, cnt, E);
    offsets_kernel<<<(N + 255) / 256, 256, 0, stream>>>(cnt, counter, beg, cur, N);
    fill_kernel<<<(E + 255) / 256, 256, 0, stream>>>(ei, flag, cur, col, E);

    // ---- weight conversion (column-major concat) ----
    convert_w_kernel<<<(512 * 320 + 255) / 256, 256, 0, stream>>>(W1l, W1r, wt1, IN_CH, 320);
    convert_w_kernel<<<(512 * 256 + 255) / 256, 256, 0, stream>>>(W2l, W2r, wt2, HID, 256);

    const dim3 ggrid((N + 127) / 128, 2);  // y: 0=Y block, 1=Z block

    // ---- layer 1: y=x@W1l (bf16), z1(d_out,bf16)=x@W1r+b1 ; h=relu(mean+z1) ----
    mfma_gemm_kernel<320, true, true><<<ggrid, 512, 0, stream>>>(x, wt1, b1, y, z1, N);
    gather_agg_kernel<true><<<(N + 3) / 4, 256, 0, stream>>>(y, beg, cnt, col, z1, hb, N);

    // ---- layer 2: y=h@W2l, z(d_out,fp32)=h@W2r+b2 ; out = mean+z ----
    mfma_gemm_kernel<256, false, false><<<ggrid, 512, 0, stream>>>(hb, wt2, b2, y, out, N);
    gather_agg_kernel<false><<<(N + 3) / 4, 256, 0, stream>>>(y, beg, cnt, col, out, out, N);
}